// Round 4
// baseline (617.395 us; speedup 1.0000x reference)
//
#include <hip/hip_runtime.h>
#include <cstdint>
#include <cstddef>

#define B_ROWS 512
#define E_DIM  512
#define C_CLS  100000
#define NT     782            // ceil(100000/128)

#define S_SC    30.0f
#define M_MRG   0.35f
#define LAMBDA_ 0.01f
#define ALPHA_  0.5f
#define EPS_    1e-6f

#define GBN    128            // cols per block tile
#define GSTEPS 16             // E_DIM / 32

typedef __attribute__((ext_vector_type(8))) short bf16x8;
typedef __attribute__((ext_vector_type(4))) float f32x4;

static_assert((size_t)NT * GBN >= C_CLS, "tile count");

// ---------------- ws layout (bytes) ----------------
constexpr size_t WS_PSUM  = 0;                                    // NT*512 f32 partial sumexp
constexpr size_t WS_PMAX  = WS_PSUM + (size_t)NT * B_ROWS * 4;    // NT*512 u32 partial max keys
constexpr size_t WS_CLOSS = WS_PMAX + (size_t)NT * B_ROWS * 4;    // [0]=closs f32, [8]=copy ctr u32 (zeroed 512B)
constexpr size_t WS_EMBN  = WS_CLOSS + 512;                       // 512*512 bf16 normalized emb
constexpr size_t WS_COSL  = WS_EMBN + (size_t)B_ROWS * E_DIM * 2; // 512 f32 cos at label (f32-exact)
constexpr size_t WS_CNT   = WS_COSL + 2048;                       // 512 f32 label counts
constexpr size_t WS_RSUM  = WS_CNT + 2048;                        // 512 f32 row sumexp (non-label)
constexpr size_t WS_RMAX  = WS_RSUM + 2048;                       // 512 f32 row max   (non-label)

// ---------------- helpers ----------------
__device__ __forceinline__ unsigned short f2bf(float f) {
    unsigned u = __float_as_uint(f);
    u += 0x7fffu + ((u >> 16) & 1u);            // round-to-nearest-even
    return (unsigned short)(u >> 16);
}
__device__ __forceinline__ unsigned fkey(float f) {   // monotonic float->uint (for atomicMax)
    unsigned u = __float_as_uint(f);
    return (u & 0x80000000u) ? ~u : (u | 0x80000000u);
}
__device__ __forceinline__ float unkey(unsigned k) {
    unsigned u = (k & 0x80000000u) ? (k ^ 0x80000000u) : ~k;
    return __uint_as_float(u);
}
__device__ __forceinline__ float waveReduceSum(float v) {
#pragma unroll
    for (int d = 1; d < 64; d <<= 1) v += __shfl_xor(v, d, 64);
    return v;
}
__device__ __forceinline__ unsigned waveReduceMax(unsigned v) {
#pragma unroll
    for (int d = 1; d < 64; d <<= 1) { unsigned o = __shfl_xor(v, d, 64); v = o > v ? o : v; }
    return v;
}
__device__ __forceinline__ float blockReduceSum256(float v, float* s4) {
    v = waveReduceSum(v);
    int w = threadIdx.x >> 6;
    if ((threadIdx.x & 63) == 0) s4[w] = v;
    __syncthreads();
    float r = s4[0] + s4[1] + s4[2] + s4[3];
    __syncthreads();
    return r;
}

// ---------------- kernels ----------------

// merged emb_prep + label_stats: normalize emb rows -> bf16; f32-exact label cosine,
// label count, center-loss accum. One block per sample.
__global__ __launch_bounds__(256) void prep_stats(const float* __restrict__ emb,
                                                  const float* __restrict__ W,
                                                  const float* __restrict__ centers,
                                                  const int* __restrict__ label,
                                                  unsigned short* __restrict__ embn,
                                                  float* __restrict__ cosl,
                                                  float* __restrict__ cntf,
                                                  float* __restrict__ closs) {
    __shared__ float s4[4];
    int b = blockIdx.x, t = threadIdx.x;
    int lab = label[b];
    float2 e2 = *(const float2*)(emb     + (size_t)b   * E_DIM + t * 2);
    float2 w2 = *(const float2*)(W       + (size_t)lab * E_DIM + t * 2);
    float2 c2 = *(const float2*)(centers + (size_t)lab * E_DIM + t * 2);
    float ssq = e2.x * e2.x + e2.y * e2.y;
    float d   = e2.x * w2.x + e2.y * w2.y;
    float wss = w2.x * w2.x + w2.y * w2.y;
    float dx = e2.x - c2.x, dy = e2.y - c2.y;
    float sq  = dx * dx + dy * dy;
    float cn = ((label[t] == lab) ? 1.f : 0.f) + ((label[t + 256] == lab) ? 1.f : 0.f);
    ssq = blockReduceSum256(ssq, s4);
    d   = blockReduceSum256(d,   s4);
    wss = blockReduceSum256(wss, s4);
    sq  = blockReduceSum256(sq,  s4);
    cn  = blockReduceSum256(cn,  s4);
    float inv = 1.0f / sqrtf(ssq);
    ushort2 o; o.x = f2bf(e2.x * inv); o.y = f2bf(e2.y * inv);
    *(ushort2*)(embn + (size_t)b * E_DIM + t * 2) = o;
    if (t == 0) {
        cosl[b] = d * inv / sqrtf(wss);
        cntf[b] = cn;
        atomicAdd(closs, sq);
    }
}

// ---------- fused GEMM + centers-copy ----------
// BM=512 (whole batch), BN=128, K-step=32. A fragments come straight from L2 (embn is
// 512 KB, fully cached, shared by all blocks) -- no LDS for A. B: raw f32 W reg-staged
// (accumulating row sum-of-squares for the norm), RNE-cvt to bf16, one swizzled
// ds_write_b128 per thread per step into a double-buffered 8 KB slot.
// After the epilogue, blocks steal 64-KB chunks of the centers->out copy via a global
// atomic counter claimed ONCE PER BLOCK (tid0 + LDS broadcast): hides the 410 MB copy
// under gemm and fills the 782-vs-256 block tail.
__global__ __launch_bounds__(512, 1) void gemm_fused(const unsigned short* __restrict__ embn,
                                                     const float* __restrict__ W,
                                                     const int* __restrict__ label,
                                                     float* __restrict__ psum,
                                                     unsigned* __restrict__ pmax,
                                                     const float* __restrict__ centers,
                                                     float* __restrict__ outC,
                                                     unsigned* __restrict__ ctr) {
    __shared__ __align__(16) unsigned short sB[2][GBN * 32];   // 2 x 8 KiB bf16
    __shared__ int      sLab[B_ROWS];
    __shared__ float    sInv[GBN];
    __shared__ unsigned sChunk;

    const int tid  = threadIdx.x;            // 0..511, 8 waves
    const int lane = tid & 63, wave = tid >> 6;
    const int wm = wave >> 1, wn = wave & 1; // wm: 128-row block, wn: 64-col half
    const int q = lane >> 4, lm = lane & 15;
    const int n0 = blockIdx.x * GBN;

    sLab[tid & (B_ROWS - 1)] = label[tid & (B_ROWS - 1)];

    // ---- B staging descriptors (thread owns row brow, logical 8-f32 granule bl) ----
    const int brow = tid >> 2;               // 0..127
    const int bl   = tid & 3;
    int brg = n0 + brow; if (brg >= C_CLS) brg = 0;      // clamp OOB rows (excluded later)
    const float* bsrc = W + (size_t)brg * E_DIM + bl * 8;
    const int bphys = bl ^ ((brow >> 1) & 3);            // XOR swizzle: bank-spread reads
    unsigned short* bwr = &sB[0][brow * 32 + bphys * 8]; // slot1 = +4096 shorts

    // ---- A fragment source pointers (direct from L2) ----
    const unsigned short* aP[8];
#pragma unroll
    for (int i = 0; i < 8; ++i)
        aP[i] = embn + (size_t)(wm * 128 + i * 16 + lm) * E_DIM + q * 8;

    // ---- B fragment LDS read pointers (swizzled) ----
    const unsigned short* brd[4];
#pragma unroll
    for (int j = 0; j < 4; ++j) {
        int row = wn * 64 + j * 16 + lm;
        brd[j] = &sB[0][row * 32 + (q ^ ((row >> 1) & 3)) * 8];
    }

    f32x4 acc[8][4];
#pragma unroll
    for (int i = 0; i < 8; ++i)
#pragma unroll
        for (int j = 0; j < 4; ++j) acc[i][j] = (f32x4){0.f, 0.f, 0.f, 0.f};

    float ss = 0.f;
    f32x4 bA0, bA1, bB0, bB1;                // two in-flight B f32 reg sets

    // ---- prologue: B(0) -> slot0; issue B(1) ----
    bA0 = *(const f32x4*)(bsrc + 0);
    bA1 = *(const f32x4*)(bsrc + 4);
    bB0 = *(const f32x4*)(bsrc + 32);        // B(1), stays in flight
    bB1 = *(const f32x4*)(bsrc + 36);
    {
        ss += bA0.x*bA0.x + bA0.y*bA0.y + bA0.z*bA0.z + bA0.w*bA0.w
            + bA1.x*bA1.x + bA1.y*bA1.y + bA1.z*bA1.z + bA1.w*bA1.w;
        bf16x8 o;
        o[0] = (short)f2bf(bA0.x); o[1] = (short)f2bf(bA0.y);
        o[2] = (short)f2bf(bA0.z); o[3] = (short)f2bf(bA0.w);
        o[4] = (short)f2bf(bA1.x); o[5] = (short)f2bf(bA1.y);
        o[6] = (short)f2bf(bA1.z); o[7] = (short)f2bf(bA1.w);
        *(bf16x8*)bwr = o;
    }
    asm volatile("s_waitcnt lgkmcnt(0)" ::: "memory");
    __builtin_amdgcn_sched_barrier(0);
    __builtin_amdgcn_s_barrier();

    // ---- main loop: 16 K-steps, fully unrolled (pragma unroll folds t_ per iteration),
    // B f32 regs ping-pong ----
#define STEP(T, WR0, WR1, LD0, LD1)                                             \
    {                                                                           \
        const int t_ = (T);                                                     \
        bf16x8 af[8];                                                           \
        _Pragma("unroll")                                                       \
        for (int i = 0; i < 8; ++i)                                             \
            af[i] = *(const bf16x8*)(aP[i] + t_ * 32);                          \
        if (t_ + 2 < GSTEPS) {                                                  \
            LD0 = *(const f32x4*)(bsrc + (t_ + 2) * 32);                        \
            LD1 = *(const f32x4*)(bsrc + (t_ + 2) * 32 + 4);                    \
        }                                                                       \
        if (t_ + 1 < GSTEPS) {                                                  \
            ss += WR0.x*WR0.x + WR0.y*WR0.y + WR0.z*WR0.z + WR0.w*WR0.w         \
                + WR1.x*WR1.x + WR1.y*WR1.y + WR1.z*WR1.z + WR1.w*WR1.w;        \
            bf16x8 o;                                                           \
            o[0] = (short)f2bf(WR0.x); o[1] = (short)f2bf(WR0.y);               \
            o[2] = (short)f2bf(WR0.z); o[3] = (short)f2bf(WR0.w);               \
            o[4] = (short)f2bf(WR1.x); o[5] = (short)f2bf(WR1.y);               \
            o[6] = (short)f2bf(WR1.z); o[7] = (short)f2bf(WR1.w);               \
            *(bf16x8*)(bwr + ((t_ + 1) & 1) * 4096) = o;                        \
        }                                                                       \
        bf16x8 bfr[4];                                                          \
        _Pragma("unroll")                                                       \
        for (int j = 0; j < 4; ++j)                                             \
            bfr[j] = *(const bf16x8*)(brd[j] + (t_ & 1) * 4096);                \
        _Pragma("unroll")                                                       \
        for (int i = 0; i < 8; ++i)                                             \
            _Pragma("unroll")                                                   \
            for (int j = 0; j < 4; ++j)                                         \
                acc[i][j] = __builtin_amdgcn_mfma_f32_16x16x32_bf16(af[i], bfr[j], acc[i][j], 0, 0, 0); \
        __builtin_amdgcn_sched_barrier(0);                                      \
        asm volatile("s_waitcnt lgkmcnt(0)" ::: "memory");                      \
        __builtin_amdgcn_sched_barrier(0);                                      \
        __builtin_amdgcn_s_barrier();                                           \
    }

#pragma unroll
    for (int tt = 0; tt < GSTEPS; tt += 2) {
        STEP(tt,     bB0, bB1, bA0, bA1);    // write B(tt+1), load B(tt+2)
        STEP(tt + 1, bA0, bA1, bB0, bB1);
    }
#undef STEP

    // ---- W row inverse norms (exact f32 sum-of-squares of raw W) ----
    ss += __shfl_xor(ss, 1, 64);
    ss += __shfl_xor(ss, 2, 64);
    if ((tid & 3) == 0) sInv[brow] = rsqrtf(fmaxf(ss, 1e-30f));
    __syncthreads();

    // ---- epilogue: exp-sum and max over this 512x128 tile (label & OOB excluded) ----
    float inv_j[4];
#pragma unroll
    for (int j = 0; j < 4; ++j) inv_j[j] = sInv[wn * 64 + j * 16 + lm];

    const size_t pbase = (size_t)blockIdx.x * B_ROWS;
#pragma unroll
    for (int i = 0; i < 8; ++i) {
#pragma unroll
        for (int r = 0; r < 4; ++r) {
            int row = wm * 128 + i * 16 + q * 4 + r;
            int lab = sLab[row];
            float sum = 0.f, mx = -1e30f;
#pragma unroll
            for (int j = 0; j < 4; ++j) {
                int col = n0 + wn * 64 + j * 16 + lm;
                float v = S_SC * acc[i][j][r] * inv_j[j];
                if (col < C_CLS && col != lab) {
                    sum += __expf(v - 30.0f);          // m_logits <= ~30 by construction
                    mx = fmaxf(mx, v);
                }
            }
#pragma unroll
            for (int d = 1; d < 16; d <<= 1) {
                sum += __shfl_xor(sum, d, 64);
                mx = fmaxf(mx, __shfl_xor(mx, d, 64));
            }
            if (lm == 0) {
                atomicAdd(&psum[pbase + row], sum);    // 2 adds/addr: commutative
                atomicMax(&pmax[pbase + row], fkey(mx));
            }
        }
    }

    // ---- centers -> out copy, BLOCK-level work-stealing (chunk claimed once per block,
    // broadcast via LDS; all 512 threads cooperate on the 4096-float4 chunk) ----
    constexpr size_t N4 = ((size_t)C_CLS * E_DIM - 2) / 4;   // float4 groups from element 2
    constexpr unsigned NCHUNK = (unsigned)((N4 + 4095) / 4096);
    const float2* s2 = (const float2*)(centers + 2);
    float4* d4 = (float4*)(outC + 2);                        // outC+2 is 16B-aligned
    for (;;) {
        if (tid == 0) sChunk = atomicAdd(ctr, 1u);
        __syncthreads();
        unsigned c = sChunk;
        __syncthreads();                                     // all read before next claim
        if (c >= NCHUNK) break;                              // uniform exit
        size_t g0 = (size_t)c * 4096;
#pragma unroll
        for (int u = 0; u < 8; ++u) {
            size_t g = g0 + (size_t)u * 512 + tid;
            if (g < N4) {
                float2 a = s2[2 * g], b = s2[2 * g + 1];
                d4[g] = make_float4(a.x, a.y, b.x, b.y);
            }
        }
        if (c == 0 && tid == 0) {
            *(float2*)outC = *(const float2*)centers;        // elements 0,1
            constexpr size_t t0 = 2 + 4 * N4;                // last 2 elements
            *(float2*)(outC + t0) = *(const float2*)(centers + t0);
        }
    }
}

// fixed-order reduction over the 782 tile-partials per row (deterministic)
__global__ __launch_bounds__(256) void row_reduce(const float* __restrict__ psum,
                                                  const unsigned* __restrict__ pmax,
                                                  float* __restrict__ rsum,
                                                  float* __restrict__ rmax) {
    __shared__ float s4[4];
    __shared__ unsigned m4[4];
    int b = blockIdx.x, t = threadIdx.x;
    float s = 0.f; unsigned mk = 0u;
    for (int nt = t; nt < NT; nt += 256) {
        s += psum[(size_t)nt * B_ROWS + b];
        unsigned k = pmax[(size_t)nt * B_ROWS + b];
        mk = k > mk ? k : mk;
    }
    s = waveReduceSum(s);
    mk = waveReduceMax(mk);
    int w = t >> 6;
    if ((t & 63) == 0) { s4[w] = s; m4[w] = mk; }
    __syncthreads();
    if (t == 0) {
        rsum[b] = s4[0] + s4[1] + s4[2] + s4[3];
        unsigned m = m4[0];
#pragma unroll
        for (int i = 1; i < 4; ++i) m = m4[i] > m ? m4[i] : m;
        rmax[b] = unkey(m);
    }
}

__global__ __launch_bounds__(256) void finalize(const float* __restrict__ cosl,
                                                const float* __restrict__ rsum,
                                                const float* __restrict__ rmax,
                                                const float* __restrict__ closs,
                                                float* __restrict__ out) {
    __shared__ float s4[4];
    int t = threadIdx.x;
    float lsum = 0.f, msum = 0.f;
    for (int b = t; b < B_ROWS; b += 256) {
        float lv = S_SC * (cosl[b] - M_MRG);
        float tot = rsum[b] + __expf(lv - 30.0f);
        lsum += (logf(tot) + 30.0f) - lv;
        msum += (lv > rmax[b]) ? 1.0f : 0.0f;
    }
    lsum = blockReduceSum256(lsum, s4);
    msum = blockReduceSum256(msum, s4);
    if (t == 0) {
        out[0] = msum * (100.0f / (float)B_ROWS);
        out[1] = lsum * (1.0f / (float)B_ROWS)
               + LAMBDA_ * closs[0] * (1.0f / ((float)B_ROWS * (float)E_DIM));
    }
}

// scatter: new_centers[label[b]] += alpha*(e - c)/(count+eps)
__global__ __launch_bounds__(256) void scatter_upd(const float* __restrict__ emb,
                                                   const float* __restrict__ centers,
                                                   const int* __restrict__ label,
                                                   const float* __restrict__ cntf,
                                                   float* __restrict__ outC) {
    int b = blockIdx.x, t = threadIdx.x;
    int lab = label[b];
    float sc = ALPHA_ / (cntf[b] + EPS_);
    for (int c = t; c < E_DIM; c += 256) {
        float add = sc * (emb[(size_t)b * E_DIM + c] - centers[(size_t)lab * E_DIM + c]);
        atomicAdd(outC + (size_t)lab * E_DIM + c, add);
    }
}

// ---------------- launcher ----------------
extern "C" void kernel_launch(void* const* d_in, const int* in_sizes, int n_in,
                              void* d_out, int out_size, void* d_ws, size_t ws_size,
                              hipStream_t stream) {
    const float* emb     = (const float*)d_in[0];
    const float* W       = (const float*)d_in[1];
    const float* centers = (const float*)d_in[2];
    const int*   label   = (const int*)d_in[3];
    float* out = (float*)d_out;
    char* ws = (char*)d_ws;

    float*          psum = (float*)(ws + WS_PSUM);
    unsigned*       pmax = (unsigned*)(ws + WS_PMAX);
    float*          closs = (float*)(ws + WS_CLOSS);
    unsigned*       ctr  = (unsigned*)(ws + WS_CLOSS + 8);
    unsigned short* embn = (unsigned short*)(ws + WS_EMBN);
    float*          cosl = (float*)(ws + WS_COSL);
    float*          cntf = (float*)(ws + WS_CNT);
    float*          rsum = (float*)(ws + WS_RSUM);
    float*          rmax = (float*)(ws + WS_RMAX);

    // zero psum + pmax (gemm accumulates via global atomics) + closs + copy ctr
    (void)hipMemsetAsync(ws, 0, WS_CLOSS + 512, stream);

    prep_stats<<<B_ROWS, 256, 0, stream>>>(emb, W, centers, label, embn, cosl, cntf, closs);
    gemm_fused<<<NT, 512, 0, stream>>>(embn, W, label, psum, pmax, centers, out + 2, ctr);
    row_reduce<<<B_ROWS, 256, 0, stream>>>(psum, pmax, rsum, rmax);
    finalize<<<1, 256, 0, stream>>>(cosl, rsum, rmax, closs, out);
    scatter_upd<<<B_ROWS, 256, 0, stream>>>(emb, centers, label, cntf, out + 2);
}

// Round 6
// 595.156 us; speedup vs baseline: 1.0374x; 1.0374x over previous
//
#include <hip/hip_runtime.h>
#include <cstdint>
#include <cstddef>

#define B_ROWS 512
#define E_DIM  512
#define C_CLS  100000
#define NT     782            // ceil(100000/128)

#define S_SC    30.0f
#define M_MRG   0.35f
#define LAMBDA_ 0.01f
#define ALPHA_  0.5f
#define EPS_    1e-6f

#define GBN    128            // cols per block tile
#define GSTEPS 16             // E_DIM / 32
#define ASLOT  (512 * 32)     // shorts per A slot (512 rows x 32 k)
#define BSLOT  (128 * 32)     // shorts per B slot (128 rows x 32 k)

typedef __attribute__((ext_vector_type(8))) short bf16x8;
typedef __attribute__((ext_vector_type(4))) float f32x4;

static_assert((size_t)NT * GBN >= C_CLS, "tile count");

// ---------------- ws layout (bytes) ----------------
constexpr size_t WS_PSUM  = 0;                                    // NT*512 f32 partial sumexp
constexpr size_t WS_PMAX  = WS_PSUM + (size_t)NT * B_ROWS * 4;    // NT*512 u32 partial max keys
constexpr size_t WS_CLOSS = WS_PMAX + (size_t)NT * B_ROWS * 4;    // [0]=closs f32 (zeroed 512B)
constexpr size_t WS_EMBN  = WS_CLOSS + 512;                       // 512*512 bf16 normalized emb
constexpr size_t WS_COSL  = WS_EMBN + (size_t)B_ROWS * E_DIM * 2; // 512 f32 cos at label (f32-exact)
constexpr size_t WS_CNT   = WS_COSL + 2048;                       // 512 f32 label counts
constexpr size_t WS_RSUM  = WS_CNT + 2048;                        // 512 f32 row sumexp (non-label)
constexpr size_t WS_RMAX  = WS_RSUM + 2048;                       // 512 f32 row max   (non-label)

// ---------------- helpers ----------------
__device__ __forceinline__ unsigned short f2bf(float f) {
    unsigned u = __float_as_uint(f);
    u += 0x7fffu + ((u >> 16) & 1u);            // round-to-nearest-even
    return (unsigned short)(u >> 16);
}
__device__ __forceinline__ unsigned fkey(float f) {   // monotonic float->uint (for atomicMax)
    unsigned u = __float_as_uint(f);
    return (u & 0x80000000u) ? ~u : (u | 0x80000000u);
}
__device__ __forceinline__ float unkey(unsigned k) {
    unsigned u = (k & 0x80000000u) ? (k ^ 0x80000000u) : ~k;
    return __uint_as_float(u);
}
__device__ __forceinline__ float waveReduceSum(float v) {
#pragma unroll
    for (int d = 1; d < 64; d <<= 1) v += __shfl_xor(v, d, 64);
    return v;
}
__device__ __forceinline__ unsigned waveReduceMax(unsigned v) {
#pragma unroll
    for (int d = 1; d < 64; d <<= 1) { unsigned o = __shfl_xor(v, d, 64); v = o > v ? o : v; }
    return v;
}
__device__ __forceinline__ float blockReduceSum256(float v, float* s4) {
    v = waveReduceSum(v);
    int w = threadIdx.x >> 6;
    if ((threadIdx.x & 63) == 0) s4[w] = v;
    __syncthreads();
    float r = s4[0] + s4[1] + s4[2] + s4[3];
    __syncthreads();
    return r;
}
// async global->LDS, 16 B per lane. LDS dest = wave-uniform base + lane*16.
__device__ __forceinline__ void g2l16(const void* g, void* l) {
    __builtin_amdgcn_global_load_lds(
        (const __attribute__((address_space(1))) unsigned int*)g,
        (__attribute__((address_space(3))) unsigned int*)l, 16, 0, 0);
}

// ---------------- kernels ----------------

// merged emb_prep + label_stats: normalize emb rows -> bf16; f32-exact label cosine,
// label count, center-loss accum. One block per sample.
__global__ __launch_bounds__(256) void prep_stats(const float* __restrict__ emb,
                                                  const float* __restrict__ W,
                                                  const float* __restrict__ centers,
                                                  const int* __restrict__ label,
                                                  unsigned short* __restrict__ embn,
                                                  float* __restrict__ cosl,
                                                  float* __restrict__ cntf,
                                                  float* __restrict__ closs) {
    __shared__ float s4[4];
    int b = blockIdx.x, t = threadIdx.x;
    int lab = label[b];
    float2 e2 = *(const float2*)(emb     + (size_t)b   * E_DIM + t * 2);
    float2 w2 = *(const float2*)(W       + (size_t)lab * E_DIM + t * 2);
    float2 c2 = *(const float2*)(centers + (size_t)lab * E_DIM + t * 2);
    float ssq = e2.x * e2.x + e2.y * e2.y;
    float d   = e2.x * w2.x + e2.y * w2.y;
    float wss = w2.x * w2.x + w2.y * w2.y;
    float dx = e2.x - c2.x, dy = e2.y - c2.y;
    float sq  = dx * dx + dy * dy;
    float cn = ((label[t] == lab) ? 1.f : 0.f) + ((label[t + 256] == lab) ? 1.f : 0.f);
    ssq = blockReduceSum256(ssq, s4);
    d   = blockReduceSum256(d,   s4);
    wss = blockReduceSum256(wss, s4);
    sq  = blockReduceSum256(sq,  s4);
    cn  = blockReduceSum256(cn,  s4);
    float inv = 1.0f / sqrtf(ssq);
    ushort2 o; o.x = f2bf(e2.x * inv); o.y = f2bf(e2.y * inv);
    *(ushort2*)(embn + (size_t)b * E_DIM + t * 2) = o;
    if (t == 0) {
        cosl[b] = d * inv / sqrtf(wss);
        cntf[b] = cn;
        atomicAdd(closs, sq);
    }
}

// ---------- fused GEMM + centers-copy ----------
// BM=512 (whole batch, W read once), BN=128, K-step 32.
// A: staged via global_load_lds (contiguous 1KiB/wave-instr) into 3 x 32KB slots,
//    stage A(t+2) at step t, counted end-of-step vmcnt(6) keeps A(t+2)+B(t+2) in flight.
// B: raw f32 W reg-staged (2 f32x4/thread, ping-pong), RNE-cvt -> one swizzled
//    ds_write_b128 into 2 x 8KB slots; the write sits AFTER the MFMAs so its vmcnt
//    wait for B(t+1) (issued 1 step earlier) is fully covered by compute.
// Swizzle (both A and B): phys 8-short granule p of row r holds logical l = p^((r>>1)&3);
//    applied via pre-swizzled GLOBAL source for A (g2l16 writes linearly) and via
//    swizzled ds_write addr for B; reads use pq8 = (q^((lm>>1)&3))*8.
// After the epilogue: static per-block 256KB slice of the centers->out copy (no atomics);
//    round-2/3 blocks' GEMM overlaps round-1 blocks' copy, and the copy fills the tail.
__global__ __launch_bounds__(512, 1) void gemm_fused(const unsigned short* __restrict__ embn,
                                                     const float* __restrict__ W,
                                                     const int* __restrict__ label,
                                                     float* __restrict__ psum,
                                                     unsigned* __restrict__ pmax,
                                                     const float* __restrict__ centers,
                                                     float* __restrict__ outC) {
    __shared__ __align__(16) unsigned short sA[3 * ASLOT];   // 96 KiB
    __shared__ __align__(16) unsigned short sBl[2 * BSLOT];  // 16 KiB
    __shared__ int   sLab[B_ROWS];
    __shared__ float sInv[GBN];

    const int tid  = threadIdx.x;            // 0..511, 8 waves
    const int lane = tid & 63, wave = tid >> 6;
    const int wm = wave >> 1, wn = wave & 1; // wm: 128-row block, wn: 64-col half
    const int q = lane >> 4, lm = lane & 15;
    const int n0 = blockIdx.x * GBN;

    sLab[tid] = label[tid];

    // ---- A staging source offsets (shorts), pre-swizzled ----
    // granule G = j*512 + tid: r = j*128 + (tid>>2), p = tid&3, l = p ^ ((r>>1)&3)
    const int swz = (tid & 3) ^ ((tid >> 3) & 3);
    int aOff[4];
#pragma unroll
    for (int j = 0; j < 4; ++j)
        aOff[j] = (j * 128 + (tid >> 2)) * E_DIM + swz * 8;

    // ---- B staging (thread owns row brow, logical 8-f32 granule bl) ----
    const int brow = tid >> 2;               // 0..127
    const int bl   = tid & 3;
    int brg = n0 + brow; if (brg >= C_CLS) brg = 0;      // clamp OOB rows (excluded later)
    const float* bsrc = W + (size_t)brg * E_DIM + bl * 8;
    const int bphys = bl ^ ((brow >> 1) & 3);            // XOR swizzle for bank-spread reads
    unsigned short* bwr = &sBl[brow * 32 + bphys * 8];   // slot1 = +BSLOT shorts

    // ---- fragment read offsets (shorts) ----
    const int pq8 = (q ^ ((lm >> 1) & 3)) * 8;           // swizzled granule
    int aRd[8];
#pragma unroll
    for (int i = 0; i < 8; ++i)
        aRd[i] = (wm * 128 + i * 16 + lm) * 32 + pq8;
    int bRd[4];
#pragma unroll
    for (int j = 0; j < 4; ++j)
        bRd[j] = (wn * 64 + j * 16 + lm) * 32 + pq8;

    f32x4 acc[8][4];
#pragma unroll
    for (int i = 0; i < 8; ++i)
#pragma unroll
        for (int j = 0; j < 4; ++j) acc[i][j] = (f32x4){0.f, 0.f, 0.f, 0.f};

    float ss = 0.f;
    f32x4 bA0, bA1, bB0, bB1;                // two in-flight B f32 reg sets

    // ---- prologue: stage A(0)->slot0, A(1)->slot1; load B(0),B(1); write B(0) ----
#pragma unroll
    for (int j = 0; j < 4; ++j)
        g2l16(embn + aOff[j], &sA[0 * ASLOT + (j * 512 + wave * 64) * 8]);
#pragma unroll
    for (int j = 0; j < 4; ++j)
        g2l16(embn + aOff[j] + 32, &sA[1 * ASLOT + (j * 512 + wave * 64) * 8]);
    bA0 = *(const f32x4*)(bsrc + 0);
    bA1 = *(const f32x4*)(bsrc + 4);
    bB0 = *(const f32x4*)(bsrc + 32);        // B(1), stays in flight
    bB1 = *(const f32x4*)(bsrc + 36);
    {
        ss += bA0.x*bA0.x + bA0.y*bA0.y + bA0.z*bA0.z + bA0.w*bA0.w
            + bA1.x*bA1.x + bA1.y*bA1.y + bA1.z*bA1.z + bA1.w*bA1.w;
        bf16x8 o;
        o[0] = (short)f2bf(bA0.x); o[1] = (short)f2bf(bA0.y);
        o[2] = (short)f2bf(bA0.z); o[3] = (short)f2bf(bA0.w);
        o[4] = (short)f2bf(bA1.x); o[5] = (short)f2bf(bA1.y);
        o[6] = (short)f2bf(bA1.z); o[7] = (short)f2bf(bA1.w);
        *(bf16x8*)bwr = o;                   // compiler waits vmcnt for B(0) (drains A(0,1) too)
    }
    asm volatile("s_waitcnt lgkmcnt(0)" ::: "memory");
    __builtin_amdgcn_sched_barrier(0);
    __builtin_amdgcn_s_barrier();

    // ---- main loop: 16 K-steps, fully unrolled; regions fenced with sched_barrier ----
#define STEP(T, WR0, WR1, LD0, LD1)                                             \
    {                                                                           \
        const int t_ = (T);                                                     \
        if (t_ + 2 < GSTEPS) {                                                  \
            _Pragma("unroll")                                                   \
            for (int j = 0; j < 4; ++j)                                         \
                g2l16(embn + aOff[j] + (t_ + 2) * 32,                           \
                      &sA[((t_ + 2) % 3) * ASLOT + (j * 512 + wave * 64) * 8]); \
            LD0 = *(const f32x4*)(bsrc + (t_ + 2) * 32);                        \
            LD1 = *(const f32x4*)(bsrc + (t_ + 2) * 32 + 4);                    \
        }                                                                       \
        __builtin_amdgcn_sched_barrier(0);                                      \
        {                                                                       \
            const unsigned short* sa = &sA[(t_ % 3) * ASLOT];                   \
            const unsigned short* sb = &sBl[(t_ & 1) * BSLOT];                  \
            bf16x8 af[8], bfr[4];                                               \
            _Pragma("unroll")                                                   \
            for (int i = 0; i < 8; ++i) af[i] = *(const bf16x8*)(sa + aRd[i]);  \
            _Pragma("unroll")                                                   \
            for (int j = 0; j < 4; ++j) bfr[j] = *(const bf16x8*)(sb + bRd[j]); \
            _Pragma("unroll")                                                   \
            for (int i = 0; i < 8; ++i)                                         \
                _Pragma("unroll")                                               \
                for (int j = 0; j < 4; ++j)                                     \
                    acc[i][j] = __builtin_amdgcn_mfma_f32_16x16x32_bf16(af[i], bfr[j], acc[i][j], 0, 0, 0); \
        }                                                                       \
        __builtin_amdgcn_sched_barrier(0);                                      \
        if (t_ + 1 < GSTEPS) {                                                  \
            ss += WR0.x*WR0.x + WR0.y*WR0.y + WR0.z*WR0.z + WR0.w*WR0.w         \
                + WR1.x*WR1.x + WR1.y*WR1.y + WR1.z*WR1.z + WR1.w*WR1.w;        \
            bf16x8 o;                                                           \
            o[0] = (short)f2bf(WR0.x); o[1] = (short)f2bf(WR0.y);               \
            o[2] = (short)f2bf(WR0.z); o[3] = (short)f2bf(WR0.w);               \
            o[4] = (short)f2bf(WR1.x); o[5] = (short)f2bf(WR1.y);               \
            o[6] = (short)f2bf(WR1.z); o[7] = (short)f2bf(WR1.w);               \
            *(bf16x8*)(bwr + ((t_ + 1) & 1) * BSLOT) = o;                       \
        }                                                                       \
        __builtin_amdgcn_sched_barrier(0);                                      \
        if (t_ < GSTEPS - 1) {                                                  \
            if (t_ + 2 < GSTEPS)                                                \
                asm volatile("s_waitcnt vmcnt(6) lgkmcnt(0)" ::: "memory");     \
            else                                                                \
                asm volatile("s_waitcnt vmcnt(0) lgkmcnt(0)" ::: "memory");     \
            __builtin_amdgcn_sched_barrier(0);                                  \
            __builtin_amdgcn_s_barrier();                                       \
        }                                                                       \
    }

#pragma unroll
    for (int tt = 0; tt < GSTEPS; tt += 2) {
        STEP(tt,     bB0, bB1, bA0, bA1);    // write B(tt+1), load B(tt+2)
        STEP(tt + 1, bA0, bA1, bB0, bB1);
    }
#undef STEP

    // ---- W row inverse norms (exact f32 sum-of-squares of raw W) ----
    ss += __shfl_xor(ss, 1, 64);
    ss += __shfl_xor(ss, 2, 64);
    if ((tid & 3) == 0) sInv[brow] = rsqrtf(fmaxf(ss, 1e-30f));
    __syncthreads();

    // ---- epilogue: exp-sum and max over this 512x128 tile (label & OOB excluded) ----
    float inv_j[4];
#pragma unroll
    for (int j = 0; j < 4; ++j) inv_j[j] = sInv[wn * 64 + j * 16 + lm];

    const size_t pbase = (size_t)blockIdx.x * B_ROWS;
#pragma unroll
    for (int i = 0; i < 8; ++i) {
#pragma unroll
        for (int r = 0; r < 4; ++r) {
            int row = wm * 128 + i * 16 + q * 4 + r;
            int lab = sLab[row];
            float sum = 0.f, mx = -1e30f;
#pragma unroll
            for (int j = 0; j < 4; ++j) {
                int col = n0 + wn * 64 + j * 16 + lm;
                float v = S_SC * acc[i][j][r] * inv_j[j];
                if (col < C_CLS && col != lab) {
                    sum += __expf(v - 30.0f);          // m_logits <= ~30 by construction
                    mx = fmaxf(mx, v);
                }
            }
#pragma unroll
            for (int d = 1; d < 16; d <<= 1) {
                sum += __shfl_xor(sum, d, 64);
                mx = fmaxf(mx, __shfl_xor(mx, d, 64));
            }
            if (lm == 0) {
                atomicAdd(&psum[pbase + row], sum);    // 2 adds/addr: commutative
                atomicMax(&pmax[pbase + row], fkey(mx));
            }
        }
    }

    // ---- centers -> out copy: static per-block 16384-float4 (256 KB) slice ----
    constexpr size_t N4 = ((size_t)C_CLS * E_DIM - 2) / 4;   // float4 groups from element 2
    const float2* s2 = (const float2*)(centers + 2);
    float4* d4 = (float4*)(outC + 2);                        // outC+2 is 16B-aligned
    const size_t base = (size_t)blockIdx.x * 16384;
#pragma unroll 4
    for (int u = 0; u < 32; ++u) {
        size_t g = base + (size_t)u * 512 + tid;
        if (g < N4) {
            float2 a = s2[2 * g], b = s2[2 * g + 1];
            d4[g] = make_float4(a.x, a.y, b.x, b.y);
        }
    }
    if (blockIdx.x == 0 && tid == 0) {
        *(float2*)outC = *(const float2*)centers;            // elements 0,1
        constexpr size_t t0 = 2 + 4 * N4;                    // last 2 elements
        *(float2*)(outC + t0) = *(const float2*)(centers + t0);
    }
}

// fixed-order reduction over the 782 tile-partials per row (deterministic)
__global__ __launch_bounds__(256) void row_reduce(const float* __restrict__ psum,
                                                  const unsigned* __restrict__ pmax,
                                                  float* __restrict__ rsum,
                                                  float* __restrict__ rmax) {
    __shared__ float s4[4];
    __shared__ unsigned m4[4];
    int b = blockIdx.x, t = threadIdx.x;
    float s = 0.f; unsigned mk = 0u;
    for (int nt = t; nt < NT; nt += 256) {
        s += psum[(size_t)nt * B_ROWS + b];
        unsigned k = pmax[(size_t)nt * B_ROWS + b];
        mk = k > mk ? k : mk;
    }
    s = waveReduceSum(s);
    mk = waveReduceMax(mk);
    int w = t >> 6;
    if ((t & 63) == 0) { s4[w] = s; m4[w] = mk; }
    __syncthreads();
    if (t == 0) {
        rsum[b] = s4[0] + s4[1] + s4[2] + s4[3];
        unsigned m = m4[0];
#pragma unroll
        for (int i = 1; i < 4; ++i) m = m4[i] > m ? m4[i] : m;
        rmax[b] = unkey(m);
    }
}

__global__ __launch_bounds__(256) void finalize(const float* __restrict__ cosl,
                                                const float* __restrict__ rsum,
                                                const float* __restrict__ rmax,
                                                const float* __restrict__ closs,
                                                float* __restrict__ out) {
    __shared__ float s4[4];
    int t = threadIdx.x;
    float lsum = 0.f, msum = 0.f;
    for (int b = t; b < B_ROWS; b += 256) {
        float lv = S_SC * (cosl[b] - M_MRG);
        float tot = rsum[b] + __expf(lv - 30.0f);
        lsum += (logf(tot) + 30.0f) - lv;
        msum += (lv > rmax[b]) ? 1.0f : 0.0f;
    }
    lsum = blockReduceSum256(lsum, s4);
    msum = blockReduceSum256(msum, s4);
    if (t == 0) {
        out[0] = msum * (100.0f / (float)B_ROWS);
        out[1] = lsum * (1.0f / (float)B_ROWS)
               + LAMBDA_ * closs[0] * (1.0f / ((float)B_ROWS * (float)E_DIM));
    }
}

// scatter: new_centers[label[b]] += alpha*(e - c)/(count+eps)
__global__ __launch_bounds__(256) void scatter_upd(const float* __restrict__ emb,
                                                   const float* __restrict__ centers,
                                                   const int* __restrict__ label,
                                                   const float* __restrict__ cntf,
                                                   float* __restrict__ outC) {
    int b = blockIdx.x, t = threadIdx.x;
    int lab = label[b];
    float sc = ALPHA_ / (cntf[b] + EPS_);
    for (int c = t; c < E_DIM; c += 256) {
        float add = sc * (emb[(size_t)b * E_DIM + c] - centers[(size_t)lab * E_DIM + c]);
        atomicAdd(outC + (size_t)lab * E_DIM + c, add);
    }
}

// ---------------- launcher ----------------
extern "C" void kernel_launch(void* const* d_in, const int* in_sizes, int n_in,
                              void* d_out, int out_size, void* d_ws, size_t ws_size,
                              hipStream_t stream) {
    const float* emb     = (const float*)d_in[0];
    const float* W       = (const float*)d_in[1];
    const float* centers = (const float*)d_in[2];
    const int*   label   = (const int*)d_in[3];
    float* out = (float*)d_out;
    char* ws = (char*)d_ws;

    float*          psum = (float*)(ws + WS_PSUM);
    unsigned*       pmax = (unsigned*)(ws + WS_PMAX);
    float*          closs = (float*)(ws + WS_CLOSS);
    unsigned short* embn = (unsigned short*)(ws + WS_EMBN);
    float*          cosl = (float*)(ws + WS_COSL);
    float*          cntf = (float*)(ws + WS_CNT);
    float*          rsum = (float*)(ws + WS_RSUM);
    float*          rmax = (float*)(ws + WS_RMAX);

    // zero psum + pmax (gemm accumulates via global atomics) + closs
    (void)hipMemsetAsync(ws, 0, WS_CLOSS + 512, stream);

    prep_stats<<<B_ROWS, 256, 0, stream>>>(emb, W, centers, label, embn, cosl, cntf, closs);
    gemm_fused<<<NT, 512, 0, stream>>>(embn, W, label, psum, pmax, centers, out + 2);
    row_reduce<<<B_ROWS, 256, 0, stream>>>(psum, pmax, rsum, rmax);
    finalize<<<1, 256, 0, stream>>>(cosl, rsum, rmax, closs, out);
    scatter_upd<<<B_ROWS, 256, 0, stream>>>(emb, centers, label, cntf, out + 2);
}